// Round 3
// baseline (128.065 us; speedup 1.0000x reference)
//
#include <hip/hip_runtime.h>
#include <hip/hip_bf16.h>
#include <math.h>

#define N_ROWS 4096
#define D_DIM  128
#define M_ROWS 8192
#define INV_T  10.0f
// sqrt(10/ln2): zn scaled so Gram(zn) = 10*log2(e)*cos  =>  exp2(Gram) = e^(10*cos)
#define BF_SCALE 3.79828218f

#if __has_builtin(__builtin_amdgcn_exp2f)
#define EXP2(x) __builtin_amdgcn_exp2f(x)
#else
#define EXP2(x) exp2f(x)
#endif

typedef __attribute__((ext_vector_type(8))) short bf16x8;
typedef __attribute__((ext_vector_type(4))) float f32x4;

// LDS-only barrier: does NOT drain vmcnt, so global prefetch stays in flight
// across the step boundary (plain __syncthreads emits s_waitcnt vmcnt(0)).
__device__ __forceinline__ void barrier_lds() {
    asm volatile("s_waitcnt lgkmcnt(0)\n\ts_barrier" ::: "memory");
}

// --- Kernel 1: fused normalize (scaled bf16) + pos ---
// One wave per row-pair i: handles z1_i and z2_i (128 floats each).
__global__ __launch_bounds__(256) void prep_kernel(
    const float* __restrict__ z1, const float* __restrict__ z2,
    ushort* __restrict__ zn, float* __restrict__ pos)
{
    const int i    = blockIdx.x * 4 + (threadIdx.x >> 6);
    const int lane = threadIdx.x & 63;
    float2 a = ((const float2*)(z1 + (size_t)i * D_DIM))[lane];
    float2 b = ((const float2*)(z2 + (size_t)i * D_DIM))[lane];
    float s11 = a.x * a.x + a.y * a.y;
    float s22 = b.x * b.x + b.y * b.y;
    float s12 = a.x * b.x + a.y * b.y;
    #pragma unroll
    for (int m = 1; m < 64; m <<= 1) {
        s11 += __shfl_xor(s11, m, 64);
        s22 += __shfl_xor(s22, m, 64);
        s12 += __shfl_xor(s12, m, 64);
    }
    float inv1 = 1.0f / fmaxf(sqrtf(s11), 1e-8f);
    float inv2 = 1.0f / fmaxf(sqrtf(s22), 1e-8f);
    if (lane == 0) pos[i] = 2.0f * INV_T * s12 * inv1 * inv2;
    const float sa = inv1 * BF_SCALE, sb = inv2 * BF_SCALE;
    __hip_bfloat16 h;
    ushort2 oa, ob;
    h = __float2bfloat16(a.x * sa); oa.x = *(const ushort*)&h;
    h = __float2bfloat16(a.y * sa); oa.y = *(const ushort*)&h;
    h = __float2bfloat16(b.x * sb); ob.x = *(const ushort*)&h;
    h = __float2bfloat16(b.y * sb); ob.y = *(const ushort*)&h;
    ((ushort2*)zn)[(size_t)i * 64 + lane] = oa;
    ((ushort2*)zn)[(size_t)(i + N_ROWS) * 64 + lane] = ob;
}

// --- Kernel 2: S[i] = sum_{j != i} exp(sim[i][j]) via bf16 MFMA, LDS-staged ---
__global__ __launch_bounds__(256) void simsum_kernel(
    const short* __restrict__ zn, float* __restrict__ S)
{
    __shared__ uint4 lbuf[2][64 * 16];   // [buf][row*16 + chunk], 16KiB each
    const int lane = threadIdx.x & 63;
    const int w    = threadIdx.x >> 6;
    const int m    = lane & 15;
    const int q    = lane >> 4;
    const int rowBase = blockIdx.y * 128 + w * 32;
    const int colBase = blockIdx.x * 512;

    // A fragments: 2 row-sets x 4 K-steps, in registers for the whole kernel
    bf16x8 afrag[2][4];
    #pragma unroll
    for (int h = 0; h < 2; ++h) {
        const short* ar = zn + (size_t)(rowBase + h * 16 + m) * D_DIM + q * 8;
        #pragma unroll
        for (int s = 0; s < 4; ++s) afrag[h][s] = *(const bf16x8*)(ar + s * 32);
    }

    const int srr = lane >> 4;
    const int sc  = lane & 15;
    uint4 regs[4];

    auto gload = [&](int step) {
        #pragma unroll
        for (int k = 0; k < 4; ++k) {
            int lr   = w * 16 + k * 4 + srr;
            int grow = colBase + step * 64 + lr;
            regs[k] = *((const uint4*)(zn + (size_t)grow * D_DIM) + sc);
        }
    };
    auto swrite = [&](int buf) {
        #pragma unroll
        for (int k = 0; k < 4; ++k) {
            int lr = w * 16 + k * 4 + srr;
            lbuf[buf][lr * 16 + (sc ^ (lr & 15))] = regs[k];
        }
    };

    gload(0);
    swrite(0);
    gload(1);
    barrier_lds();

    float rsum[8] = {0.f, 0.f, 0.f, 0.f, 0.f, 0.f, 0.f, 0.f};

    #pragma unroll
    for (int step = 0; step < 8; ++step) {
        const short* lb = (const short*)lbuf[step & 1];
        #pragma unroll
        for (int ct = 0; ct < 4; ++ct) {
            f32x4 acc0 = {0.f, 0.f, 0.f, 0.f};
            f32x4 acc1 = {0.f, 0.f, 0.f, 0.f};
            #pragma unroll
            for (int s = 0; s < 4; ++s) {
                bf16x8 bfrag = *(const bf16x8*)(lb + (ct * 16 + m) * D_DIM
                                                + (((q + s * 4) ^ m) * 8));
                acc0 = __builtin_amdgcn_mfma_f32_16x16x32_bf16(afrag[0][s], bfrag, acc0, 0, 0, 0);
                acc1 = __builtin_amdgcn_mfma_f32_16x16x32_bf16(afrag[1][s], bfrag, acc1, 0, 0, 0);
            }
            const int tileCol = colBase + step * 64 + ct * 16;
            float e0[4], e1[4];
            #pragma unroll
            for (int r = 0; r < 4; ++r) { e0[r] = EXP2(acc0[r]); e1[r] = EXP2(acc1[r]); }
            // diagonal mask: wave-uniform branch, taken once per wave in 1/16 blocks
            if (tileCol == rowBase) {
                #pragma unroll
                for (int r = 0; r < 4; ++r) if (m == q * 4 + r) e0[r] = 0.f;
            }
            if (tileCol == rowBase + 16) {
                #pragma unroll
                for (int r = 0; r < 4; ++r) if (m == q * 4 + r) e1[r] = 0.f;
            }
            #pragma unroll
            for (int r = 0; r < 4; ++r) { rsum[r] += e0[r]; rsum[4 + r] += e1[r]; }
        }
        if (step + 1 < 8) {
            swrite((step + 1) & 1);
            if (step + 2 < 8) gload(step + 2);
        }
        barrier_lds();
    }

    #pragma unroll
    for (int msk = 1; msk < 16; msk <<= 1) {
        #pragma unroll
        for (int r = 0; r < 8; ++r) rsum[r] += __shfl_xor(rsum[r], msk, 64);
    }
    if (m < 4) {
        atomicAdd(&S[rowBase + q * 4 + m],      rsum[m]);
        atomicAdd(&S[rowBase + 16 + q * 4 + m], rsum[4 + m]);
    }
}

// --- Kernel 3: out += (1/M^2) * sum_i [ log(S_i + exp(pos_i)) - pos_i ] ---
__global__ __launch_bounds__(1024) void loss_kernel(
    const float* __restrict__ S, const float* __restrict__ pos,
    float* __restrict__ out)
{
    const int i = blockIdx.x * 1024 + threadIdx.x;
    float p = pos[i & (N_ROWS - 1)];
    float v = __logf(S[i] + __expf(p)) - p;
    #pragma unroll
    for (int msk = 1; msk < 64; msk <<= 1) v += __shfl_xor(v, msk, 64);
    __shared__ float red[16];
    if ((threadIdx.x & 63) == 0) red[threadIdx.x >> 6] = v;
    __syncthreads();
    if (threadIdx.x == 0) {
        float t = 0.f;
        #pragma unroll
        for (int wv = 0; wv < 16; ++wv) t += red[wv];
        atomicAdd(out, t * (1.0f / ((float)M_ROWS * (float)M_ROWS)));
    }
}

extern "C" void kernel_launch(void* const* d_in, const int* in_sizes, int n_in,
                              void* d_out, int out_size, void* d_ws, size_t ws_size,
                              hipStream_t stream)
{
    const float* z1 = (const float*)d_in[0];
    const float* z2 = (const float*)d_in[1];
    float* out = (float*)d_out;

    char* wsp = (char*)d_ws;
    short* zn  = (short*)(wsp);                  // 2 MiB
    float* pos = (float*)(wsp + 2097152);        // 16 KiB
    float* S   = (float*)(wsp + 2097152 + 16384);// 32 KiB

    hipMemsetAsync(S, 0, M_ROWS * sizeof(float), stream);
    hipMemsetAsync(out, 0, sizeof(float), stream);
    prep_kernel<<<N_ROWS / 4, 256, 0, stream>>>(z1, z2, (ushort*)zn, pos);
    simsum_kernel<<<dim3(16, 64), 256, 0, stream>>>(zn, S);
    loss_kernel<<<M_ROWS / 1024, 1024, 0, stream>>>(S, pos, out);
}

// Round 4
// 127.650 us; speedup vs baseline: 1.0033x; 1.0033x over previous
//
#include <hip/hip_runtime.h>
#include <hip/hip_bf16.h>
#include <math.h>

#define N_ROWS 4096
#define D_DIM  128
#define M_ROWS 8192
#define INV_T  10.0f
// sqrt(10/ln2): zn scaled so Gram(zn) = 10*log2(e)*cos  =>  exp2(Gram) = e^(10*cos)
#define BF_SCALE 3.79828218f
#define NBLOCKS 512   // simsum grid size (32 row-blocks x 16 col-strips)

#if __has_builtin(__builtin_amdgcn_exp2f)
#define EXP2(x) __builtin_amdgcn_exp2f(x)
#else
#define EXP2(x) exp2f(x)
#endif

typedef __attribute__((ext_vector_type(8))) short bf16x8;
typedef __attribute__((ext_vector_type(4))) float f32x4;

// LDS-only barrier: does NOT drain vmcnt, so global prefetch stays in flight.
__device__ __forceinline__ void barrier_lds() {
    asm volatile("s_waitcnt lgkmcnt(0)\n\ts_barrier" ::: "memory");
}

// --- Kernel 1: fused normalize (scaled bf16) + pos + zero S/done ---
__global__ __launch_bounds__(256) void prep_kernel(
    const float* __restrict__ z1, const float* __restrict__ z2,
    ushort* __restrict__ zn, float* __restrict__ pos,
    float* __restrict__ S, unsigned* __restrict__ done)
{
    if (blockIdx.x < 32) S[blockIdx.x * 256 + threadIdx.x] = 0.f;
    if (blockIdx.x == 32 && threadIdx.x == 0) *done = 0u;

    const int i    = blockIdx.x * 4 + (threadIdx.x >> 6);
    const int lane = threadIdx.x & 63;
    float2 a = ((const float2*)(z1 + (size_t)i * D_DIM))[lane];
    float2 b = ((const float2*)(z2 + (size_t)i * D_DIM))[lane];
    float s11 = a.x * a.x + a.y * a.y;
    float s22 = b.x * b.x + b.y * b.y;
    float s12 = a.x * b.x + a.y * b.y;
    #pragma unroll
    for (int m = 1; m < 64; m <<= 1) {
        s11 += __shfl_xor(s11, m, 64);
        s22 += __shfl_xor(s22, m, 64);
        s12 += __shfl_xor(s12, m, 64);
    }
    float inv1 = 1.0f / fmaxf(sqrtf(s11), 1e-8f);
    float inv2 = 1.0f / fmaxf(sqrtf(s22), 1e-8f);
    if (lane == 0) pos[i] = 2.0f * INV_T * s12 * inv1 * inv2;
    const float sa = inv1 * BF_SCALE, sb = inv2 * BF_SCALE;
    __hip_bfloat16 h;
    ushort2 oa, ob;
    h = __float2bfloat16(a.x * sa); oa.x = *(const ushort*)&h;
    h = __float2bfloat16(a.y * sa); oa.y = *(const ushort*)&h;
    h = __float2bfloat16(b.x * sb); ob.x = *(const ushort*)&h;
    h = __float2bfloat16(b.y * sb); ob.y = *(const ushort*)&h;
    ((ushort2*)zn)[(size_t)i * 64 + lane] = oa;
    ((ushort2*)zn)[(size_t)(i + N_ROWS) * 64 + lane] = ob;
}

// --- Kernel 2: S[i] = sum_{j!=i} exp(sim[i][j]) + fused loss tail ---
// Block: 4 waves x 64 rows = 256 rows; 512-col strip in 8 steps of 64 cols.
// Each LDS B-frag read feeds 4 MFMAs (4 A row-sets held in registers).
__global__ __launch_bounds__(256, 2) void simsum_kernel(
    const short* __restrict__ zn, float* __restrict__ S,
    const float* __restrict__ pos, float* __restrict__ out,
    unsigned* __restrict__ done)
{
    __shared__ uint4 lbuf[2][64 * 16];   // 2 x 16 KiB, XOR-swizzled chunks
    const int tid  = threadIdx.x;
    const int lane = tid & 63;
    const int w    = tid >> 6;
    const int m    = lane & 15;
    const int q    = lane >> 4;
    const int rowBase = blockIdx.y * 256 + w * 64;
    const int colBase = blockIdx.x * 512;

    // A fragments: 4 row-sets x 4 K-steps, registers for whole kernel (64 VGPR)
    bf16x8 afrag[4][4];
    #pragma unroll
    for (int h = 0; h < 4; ++h) {
        const short* ar = zn + (size_t)(rowBase + h * 16 + m) * D_DIM + q * 8;
        #pragma unroll
        for (int s = 0; s < 4; ++s) afrag[h][s] = *(const bf16x8*)(ar + s * 32);
    }

    // staging: 256 threads load 64 rows x 256B per step (1KB-contig per inst)
    const int sr = tid >> 4;      // row-within-16
    const int sc = tid & 15;      // 16B chunk
    uint4 regs[4];

    auto gload = [&](int step) {
        #pragma unroll
        for (int j = 0; j < 4; ++j) {
            int r = sr + j * 16;
            regs[j] = ((const uint4*)(zn + (size_t)(colBase + step * 64 + r) * D_DIM))[sc];
        }
    };
    auto swrite = [&](int buf) {
        #pragma unroll
        for (int j = 0; j < 4; ++j) {
            int r = sr + j * 16;
            lbuf[buf][r * 16 + (sc ^ (r & 15))] = regs[j];
        }
    };

    gload(0);
    swrite(0);
    gload(1);
    barrier_lds();

    float rsum[4][4];
    #pragma unroll
    for (int h = 0; h < 4; ++h)
        #pragma unroll
        for (int r = 0; r < 4; ++r) rsum[h][r] = 0.f;

    #pragma unroll 1
    for (int step = 0; step < 8; ++step) {
        // prefetch FIRST so it overlaps this step's compute
        if (step + 1 < 8) swrite((step + 1) & 1);
        if (step + 2 < 8) gload(step + 2);

        const short* lb = (const short*)lbuf[step & 1];
        #pragma unroll
        for (int ct = 0; ct < 4; ++ct) {
            f32x4 acc[4];
            #pragma unroll
            for (int h = 0; h < 4; ++h) acc[h] = (f32x4){0.f, 0.f, 0.f, 0.f};
            #pragma unroll
            for (int s = 0; s < 4; ++s) {
                bf16x8 bfrag = *(const bf16x8*)(lb + (ct * 16 + m) * D_DIM
                                                + (((s * 4 + q) ^ m) * 8));
                #pragma unroll
                for (int h = 0; h < 4; ++h)
                    acc[h] = __builtin_amdgcn_mfma_f32_16x16x32_bf16(afrag[h][s], bfrag, acc[h], 0, 0, 0);
            }
            const int tileCol = colBase + step * 64 + ct * 16;
            #pragma unroll
            for (int h = 0; h < 4; ++h) {
                float e[4];
                #pragma unroll
                for (int r = 0; r < 4; ++r) e[r] = EXP2(acc[h][r]);
                if (tileCol == rowBase + h * 16) {   // wave-uniform diag mask
                    #pragma unroll
                    for (int r = 0; r < 4; ++r) if (m == q * 4 + r) e[r] = 0.f;
                }
                #pragma unroll
                for (int r = 0; r < 4; ++r) rsum[h][r] += e[r];
            }
        }
        barrier_lds();
    }

    #pragma unroll
    for (int msk = 1; msk < 16; msk <<= 1)
        #pragma unroll
        for (int h = 0; h < 4; ++h)
            #pragma unroll
            for (int r = 0; r < 4; ++r) rsum[h][r] += __shfl_xor(rsum[h][r], msk, 64);
    if (m < 4) {
        #pragma unroll
        for (int h = 0; h < 4; ++h)
            atomicAdd(&S[rowBase + h * 16 + q * 4 + m], rsum[h][m]);
    }

    // ---- fused loss: last block to finish reduces S -> scalar ----
    __threadfence();
    __syncthreads();
    __shared__ unsigned sprev;
    if (tid == 0) sprev = atomicAdd(done, 1u);
    __syncthreads();
    if (sprev == NBLOCKS - 1) {
        float acc = 0.f;
        for (int i = tid; i < M_ROWS; i += 256) {
            float s = __hip_atomic_load(&S[i], __ATOMIC_RELAXED, __HIP_MEMORY_SCOPE_AGENT);
            float p = pos[i & (N_ROWS - 1)];
            acc += __logf(s + __expf(p)) - p;
        }
        #pragma unroll
        for (int msk = 1; msk < 64; msk <<= 1) acc += __shfl_xor(acc, msk, 64);
        __shared__ float red[4];
        if (lane == 0) red[w] = acc;
        __syncthreads();
        if (tid == 0)
            out[0] = (red[0] + red[1] + red[2] + red[3])
                     / ((float)M_ROWS * (float)M_ROWS);
    }
}

extern "C" void kernel_launch(void* const* d_in, const int* in_sizes, int n_in,
                              void* d_out, int out_size, void* d_ws, size_t ws_size,
                              hipStream_t stream)
{
    const float* z1 = (const float*)d_in[0];
    const float* z2 = (const float*)d_in[1];
    float* out = (float*)d_out;

    char* wsp = (char*)d_ws;
    short* zn      = (short*)(wsp);                    // 2 MiB
    float* pos     = (float*)(wsp + 2097152);          // 16 KiB
    float* S       = (float*)(wsp + 2097152 + 16384);  // 32 KiB
    unsigned* done = (unsigned*)(wsp + 2097152 + 16384 + 32768);

    prep_kernel<<<N_ROWS / 4, 256, 0, stream>>>(z1, z2, (ushort*)zn, pos, S, done);
    simsum_kernel<<<dim3(16, 32), 256, 0, stream>>>(zn, S, pos, out, done);
}